// Round 12
// baseline (306.970 us; speedup 1.0000x reference)
//
#include <hip/hip_runtime.h>
#include <hip/hip_bf16.h>

// ---------------------------------------------------------------------------
// EncoderBlock on MI355X (gfx950). Round 12.
// r11 post-mortem: key-split redistributed work (attn unchanged) and merge
// ate the gain -> reverted. This round: cut TOTAL work on the hot pipes.
//  1) attn: direct bf16 out (no split/merge), shared Pb (46 KB, r11-verified),
//     exp2f with 0.125*log2e folded into Q (deletes v_mul per element).
//  2) QKV/FFN1 GEMMs: BK=64 via paired stride-32 sub-buffers, two
//     frag-load+MFMA passes per barrier pair (same regs as BK=32,
//     half the barriers). Pattern validated by r11's gemm_bt64.
//  3) 8 dispatches.
//
// ws layout (bytes), WS_NEED = 73416704, sentinel-guarded:
//   [0,        2097152)  wq|wk|wv|wo T (bf16)
//   [2097152,  4194304)  w1T
//   [4194304,  6291456)  w2T
//   [6291456, 14680064)  xcv: x as bf16 (8 MB)
//   [14680064,14696448)  small params (bf16)
//   A [14696448,23085056) qbuf -> t -> ff2      (8 MB)
//   B [23085056,31473664) kbuf -> y             (8 MB)
//   C [31473664,39862272) vT                    (8 MB)
//   F [39862272,73416704) ff1 (32 MB)
//   d_out                attn output scratch (bf16) -> final output (fp32)
// ---------------------------------------------------------------------------

typedef __bf16 bf16;
typedef __bf16 bf16x4 __attribute__((ext_vector_type(4)));
typedef __bf16 bf16x8 __attribute__((ext_vector_type(8)));
typedef float  f32x4  __attribute__((ext_vector_type(4)));

#define NBATCH 4
#define SEQ    2048
#define DMODEL 512
#define NHEADS 8
#define DHEAD  64
#define DFF    2048
#define MTOT   (NBATCH * SEQ)   // 8192
#define WS_NEED 73416704u
#define QSCALE (0.125f * 1.44269504f)   // 1/sqrt(dk) * log2(e), folded into Q

__device__ __forceinline__ f32x4 mfma16(bf16x8 a, bf16x8 b, f32x4 c) {
    return __builtin_amdgcn_mfma_f32_16x16x32_bf16(a, b, c, 0, 0, 0);
}

// async global->LDS, 16 B/lane. LDS dest = wave-uniform base + lane*16.
__device__ __forceinline__ void lds16(const bf16* g, bf16* l) {
    __builtin_amdgcn_global_load_lds(
        (const __attribute__((address_space(1))) void*)g,
        (__attribute__((address_space(3))) void*)l, 16, 0, 0);
}

__device__ __forceinline__ float scrub(float f) {
    return (fabsf(f) < 1e30f) ? f : 0.f;   // NaN/Inf -> 0 (no-op valid data)
}

__global__ void sentinel_kernel(bf16* out) {
    out[threadIdx.x] = (bf16)1000.0f;
}

// ---------------------------------------------------------------------------
// prep: x convert + small-param converts + all 6 weight transposes, ONE launch
// ---------------------------------------------------------------------------
__global__ __launch_bounds__(256) void prep_kernel(
        const float* x,
        const float* wq, const float* wk, const float* wv, const float* wo,
        const float* w1, const float* w2,
        const float* bq, const float* bk, const float* bv, const float* bo,
        const float* b1, const float* b2,
        const float* l1a, const float* l1b, const float* l2a, const float* l2b,
        bf16* __restrict__ xcv,
        bf16* __restrict__ wT, bf16* __restrict__ w1T, bf16* __restrict__ w2T,
        bf16* __restrict__ prm) {
    __shared__ bf16 tile[32][33];
    int b = blockIdx.x;
    if (b < 4096) {
        int i = (b * 256 + threadIdx.x) * 4;
        float4 f = *(const float4*)(x + i);
        bf16x4 o = {(bf16)scrub(f.x), (bf16)scrub(f.y),
                    (bf16)scrub(f.z), (bf16)scrub(f.w)};
        *(bf16x4*)(xcv + i) = o;
        return;
    }
    if (b < 4106) {
        int pb = b - 4096;
        const float* srcs[10] = {bq, bk, bv, bo, b1, b2, l1a, l1b, l2a, l2b};
        const int len[10] = {512,512,512,512,2048,512,512,512,512,512};
        const int dst[10] = {0,512,1024,1536,2048,4096,4608,5120,5632,6144};
        const float* s = srcs[pb];
        bf16* d = prm + dst[pb];
        for (int i = threadIdx.x; i < len[pb]; i += 256)
            d[i] = (bf16)scrub(s[i]);
        return;
    }
    const float* in; bf16* out; int K, N, bx, by;
    if (b < 5130) {
        int idx = b - 4106, z = idx >> 8, rem = idx & 255;
        const float* srcs[4] = {wq, wk, wv, wo};
        in = srcs[z]; out = wT + (size_t)z * 262144;
        K = 512; N = 512; bx = rem & 15; by = rem >> 4;
    } else if (b < 6154) {
        int idx = b - 5130;
        in = w1; out = w1T; K = 512; N = 2048; bx = idx & 63; by = idx >> 6;
    } else {
        int idx = b - 6154;
        in = w2; out = w2T; K = 2048; N = 512; bx = idx & 15; by = idx >> 4;
    }
    int tx = threadIdx.x & 31, ty = threadIdx.x >> 5;
    int n0 = bx * 32, k0 = by * 32;
#pragma unroll
    for (int i = 0; i < 4; i++) {
        int kl = ty * 4 + i;
        tile[kl][tx] = (bf16)scrub(in[(size_t)(k0 + kl) * N + n0 + tx]);
    }
    __syncthreads();
#pragma unroll
    for (int i = 0; i < 4; i++) {
        int nl = ty * 4 + i;
        out[(size_t)(n0 + nl) * K + k0 + tx] = tile[tx][nl];
    }
}

// ---------------------------------------------------------------------------
// 128x128 GEMM, BK=64 via paired stride-32 sub-buffers; two frag passes per
// barrier pair (same regs as BK=32, half the barriers).
// ---------------------------------------------------------------------------
template <bool RELU>
__global__ __launch_bounds__(256) void gemm_bt(
        const bf16* __restrict__ A, const bf16* __restrict__ BT,
        const bf16* __restrict__ bias, bf16* __restrict__ Cout,
        int M, int N, int K) {
    constexpr int BM = 128, BN = 128;
    __shared__ __align__(16) bf16 As0[BM * 32], As1[BM * 32];
    __shared__ __align__(16) bf16 Bs0[BN * 32], Bs1[BN * 32];

    int tid  = threadIdx.x;
    int wid  = tid >> 6, lane = tid & 63;
    int quad = lane >> 4, l15 = lane & 15;
    int mb = blockIdx.x * BM, nb = blockIdx.y * BN;
    int wm = (wid >> 1) * 64, wn = (wid & 1) * 64;

    f32x4 acc[4][4] = {};

    int c0 = wid * 128 + lane, c1 = c0 + 64;
    int ar0 = c0 >> 2, ac0 = (c0 & 3) * 8;
    int ar1 = c1 >> 2, ac1 = (c1 & 3) * 8;
    int o0 = wid * 1024, o1 = wid * 1024 + 512;

    for (int k0 = 0; k0 < K; k0 += 64) {
        __syncthreads();
        lds16(&A [(size_t)(mb + ar0) * K + k0 + ac0],      &As0[o0]);
        lds16(&A [(size_t)(mb + ar1) * K + k0 + ac1],      &As0[o1]);
        lds16(&A [(size_t)(mb + ar0) * K + k0 + 32 + ac0], &As1[o0]);
        lds16(&A [(size_t)(mb + ar1) * K + k0 + 32 + ac1], &As1[o1]);
        lds16(&BT[(size_t)(nb + ar0) * K + k0 + ac0],      &Bs0[o0]);
        lds16(&BT[(size_t)(nb + ar1) * K + k0 + ac1],      &Bs0[o1]);
        lds16(&BT[(size_t)(nb + ar0) * K + k0 + 32 + ac0], &Bs1[o0]);
        lds16(&BT[(size_t)(nb + ar1) * K + k0 + 32 + ac1], &Bs1[o1]);
        __syncthreads();

        bf16x8 af[4], bfr[4];
#pragma unroll
        for (int i = 0; i < 4; i++)
            af[i] = *(const bf16x8*)&As0[(wm + i * 16 + l15) * 32 + quad * 8];
#pragma unroll
        for (int j = 0; j < 4; j++)
            bfr[j] = *(const bf16x8*)&Bs0[(wn + j * 16 + l15) * 32 + quad * 8];
#pragma unroll
        for (int i = 0; i < 4; i++)
#pragma unroll
            for (int j = 0; j < 4; j++)
                acc[i][j] = mfma16(af[i], bfr[j], acc[i][j]);
#pragma unroll
        for (int i = 0; i < 4; i++)
            af[i] = *(const bf16x8*)&As1[(wm + i * 16 + l15) * 32 + quad * 8];
#pragma unroll
        for (int j = 0; j < 4; j++)
            bfr[j] = *(const bf16x8*)&Bs1[(wn + j * 16 + l15) * 32 + quad * 8];
#pragma unroll
        for (int i = 0; i < 4; i++)
#pragma unroll
            for (int j = 0; j < 4; j++)
                acc[i][j] = mfma16(af[i], bfr[j], acc[i][j]);
    }

#pragma unroll
    for (int j = 0; j < 4; j++) {
        int n = nb + wn + j * 16 + l15;
        float bv = (float)bias[n];
#pragma unroll
        for (int i = 0; i < 4; i++) {
            int mBase = mb + wm + i * 16 + quad * 4;
#pragma unroll
            for (int r = 0; r < 4; r++) {
                float v = acc[i][j][r] + bv;
                if (RELU) v = v > 0.f ? v : 0.f;
                Cout[(size_t)(mBase + r) * N + n] = (bf16)v;
            }
        }
    }
}

// ---------------------------------------------------------------------------
// BM=64, BK=64 GEMM (r11-verified) for O-proj / FFN2.
// ---------------------------------------------------------------------------
template <bool RELU>
__global__ __launch_bounds__(256) void gemm_bt64(
        const bf16* __restrict__ A, const bf16* __restrict__ BT,
        const bf16* __restrict__ bias, bf16* __restrict__ Cout,
        int M, int N, int K) {
    constexpr int BM = 64, BN = 128;
    __shared__ __align__(16) bf16 As0[BM * 32], As1[BM * 32];
    __shared__ __align__(16) bf16 Bs0[BN * 32], Bs1[BN * 32];

    int tid  = threadIdx.x;
    int wid  = tid >> 6, lane = tid & 63;
    int quad = lane >> 4, l15 = lane & 15;
    int mb = blockIdx.x * BM, nb = blockIdx.y * BN;
    int wm = (wid >> 1) * 32, wn = (wid & 1) * 64;

    f32x4 acc[2][4] = {};

    int cA = wid * 64 + lane;
    int arA = cA >> 2, acA = (cA & 3) * 8;
    int cB0 = wid * 128 + lane, cB1 = cB0 + 64;
    int br0 = cB0 >> 2, bc0 = (cB0 & 3) * 8;
    int br1 = cB1 >> 2, bc1 = (cB1 & 3) * 8;

    for (int k0 = 0; k0 < K; k0 += 64) {
        __syncthreads();
        lds16(&A [(size_t)(mb + arA) * K + k0 + acA],      &As0[wid * 512]);
        lds16(&A [(size_t)(mb + arA) * K + k0 + 32 + acA], &As1[wid * 512]);
        lds16(&BT[(size_t)(nb + br0) * K + k0 + bc0],      &Bs0[wid * 1024]);
        lds16(&BT[(size_t)(nb + br1) * K + k0 + bc1],      &Bs0[wid * 1024 + 512]);
        lds16(&BT[(size_t)(nb + br0) * K + k0 + 32 + bc0], &Bs1[wid * 1024]);
        lds16(&BT[(size_t)(nb + br1) * K + k0 + 32 + bc1], &Bs1[wid * 1024 + 512]);
        __syncthreads();

        bf16x8 a0[2], a1[2], b0[4], b1[4];
#pragma unroll
        for (int i = 0; i < 2; i++) {
            a0[i] = *(const bf16x8*)&As0[(wm + i * 16 + l15) * 32 + quad * 8];
            a1[i] = *(const bf16x8*)&As1[(wm + i * 16 + l15) * 32 + quad * 8];
        }
#pragma unroll
        for (int j = 0; j < 4; j++) {
            b0[j] = *(const bf16x8*)&Bs0[(wn + j * 16 + l15) * 32 + quad * 8];
            b1[j] = *(const bf16x8*)&Bs1[(wn + j * 16 + l15) * 32 + quad * 8];
        }
#pragma unroll
        for (int i = 0; i < 2; i++)
#pragma unroll
            for (int j = 0; j < 4; j++)
                acc[i][j] = mfma16(a1[i], b1[j], mfma16(a0[i], b0[j], acc[i][j]));
    }

#pragma unroll
    for (int j = 0; j < 4; j++) {
        int n = nb + wn + j * 16 + l15;
        float bv = (float)bias[n];
#pragma unroll
        for (int i = 0; i < 2; i++) {
            int mBase = mb + wm + i * 16 + quad * 4;
#pragma unroll
            for (int r = 0; r < 4; r++) {
                float v = acc[i][j][r] + bv;
                if (RELU) v = v > 0.f ? v : 0.f;
                Cout[(size_t)(mBase + r) * N + n] = (bf16)v;
            }
        }
    }
}

// ---------------------------------------------------------------------------
// Fused QKV GEMM, BK=64: region 0 -> Q*(QSCALE), 1 -> K, 2 -> V^T via
// LDS-transposed coalesced epilogue.
// ---------------------------------------------------------------------------
__global__ __launch_bounds__(256) void gemm_qkv(
        const bf16* __restrict__ A, const bf16* __restrict__ BT,
        const bf16* __restrict__ bias,
        bf16* __restrict__ Cq, bf16* __restrict__ Ck, bf16* __restrict__ Cv,
        int M, int N, int K) {
    constexpr int BM = 128, BN = 128;
    __shared__ __align__(16) bf16 As0[BM * 32], As1[BM * 32];
    __shared__ __align__(16) bf16 Bs0[BN * 32], Bs1[BN * 32];
    __shared__ __align__(16) bf16 Ts[128 * 136];

    int tid  = threadIdx.x;
    int wid  = tid >> 6, lane = tid & 63;
    int quad = lane >> 4, l15 = lane & 15;
    int mb = blockIdx.x * BM, nb = blockIdx.y * BN;
    int wm = (wid >> 1) * 64, wn = (wid & 1) * 64;

    f32x4 acc[4][4] = {};

    int c0 = wid * 128 + lane, c1 = c0 + 64;
    int ar0 = c0 >> 2, ac0 = (c0 & 3) * 8;
    int ar1 = c1 >> 2, ac1 = (c1 & 3) * 8;
    int o0 = wid * 1024, o1 = wid * 1024 + 512;

    for (int k0 = 0; k0 < K; k0 += 64) {
        __syncthreads();
        lds16(&A [(size_t)(mb + ar0) * K + k0 + ac0],      &As0[o0]);
        lds16(&A [(size_t)(mb + ar1) * K + k0 + ac1],      &As0[o1]);
        lds16(&A [(size_t)(mb + ar0) * K + k0 + 32 + ac0], &As1[o0]);
        lds16(&A [(size_t)(mb + ar1) * K + k0 + 32 + ac1], &As1[o1]);
        lds16(&BT[(size_t)(nb + ar0) * K + k0 + ac0],      &Bs0[o0]);
        lds16(&BT[(size_t)(nb + ar1) * K + k0 + ac1],      &Bs0[o1]);
        lds16(&BT[(size_t)(nb + ar0) * K + k0 + 32 + ac0], &Bs1[o0]);
        lds16(&BT[(size_t)(nb + ar1) * K + k0 + 32 + ac1], &Bs1[o1]);
        __syncthreads();

        bf16x8 af[4], bfr[4];
#pragma unroll
        for (int i = 0; i < 4; i++)
            af[i] = *(const bf16x8*)&As0[(wm + i * 16 + l15) * 32 + quad * 8];
#pragma unroll
        for (int j = 0; j < 4; j++)
            bfr[j] = *(const bf16x8*)&Bs0[(wn + j * 16 + l15) * 32 + quad * 8];
#pragma unroll
        for (int i = 0; i < 4; i++)
#pragma unroll
            for (int j = 0; j < 4; j++)
                acc[i][j] = mfma16(af[i], bfr[j], acc[i][j]);
#pragma unroll
        for (int i = 0; i < 4; i++)
            af[i] = *(const bf16x8*)&As1[(wm + i * 16 + l15) * 32 + quad * 8];
#pragma unroll
        for (int j = 0; j < 4; j++)
            bfr[j] = *(const bf16x8*)&Bs1[(wn + j * 16 + l15) * 32 + quad * 8];
#pragma unroll
        for (int i = 0; i < 4; i++)
#pragma unroll
            for (int j = 0; j < 4; j++)
                acc[i][j] = mfma16(af[i], bfr[j], acc[i][j]);
    }

    int reg = nb >> 9;   // 0=Q, 1=K, 2=V
    if (reg < 2) {
        bf16* C = reg ? Ck : Cq;
        float scl = reg ? 1.0f : QSCALE;
#pragma unroll
        for (int j = 0; j < 4; j++) {
            int n = nb + wn + j * 16 + l15;
            float bv = (float)bias[n];
            int nn = n & 511;
            int h = nn >> 6, dk = nn & 63;
#pragma unroll
            for (int i = 0; i < 4; i++) {
                int mBase = mb + wm + i * 16 + quad * 4;
#pragma unroll
                for (int r = 0; r < 4; r++) {
                    float v = (acc[i][j][r] + bv) * scl;
                    int m = mBase + r;
                    int b = m >> 11, s = m & (SEQ - 1);
                    C[((size_t)(b * NHEADS + h) * SEQ + s) * DHEAD + dk] = (bf16)v;
                }
            }
        }
    } else {
#pragma unroll
        for (int j = 0; j < 4; j++) {
            int nl = wn + j * 16 + l15;
            float bv = (float)bias[nb + nl];
#pragma unroll
            for (int i = 0; i < 4; i++) {
                int ml = wm + i * 16 + quad * 4;
                bf16x4 pk;
#pragma unroll
                for (int r = 0; r < 4; r++) pk[r] = (bf16)(acc[i][j][r] + bv);
                *(bf16x4*)&Ts[nl * 136 + ml] = pk;
            }
        }
        __syncthreads();
        int nl = tid >> 1, half = tid & 1;
        int nn = (nb + nl) & 511;
        int h = nn >> 6, dk = nn & 63;
        int bb = mb >> 11, s0 = mb & (SEQ - 1);
        bf16* dst = &Cv[((size_t)(bb * NHEADS + h) * DHEAD + dk) * SEQ + s0 + half * 64];
        const bf16* srcl = &Ts[nl * 136 + half * 64];
#pragma unroll
        for (int v = 0; v < 8; v++)
            *(uint4*)(dst + v * 8) = *(const uint4*)(srcl + v * 8);
    }
}

// ---------------------------------------------------------------------------
// Flash attention: grid (SEQ/128, B*H), block 256 = 4 waves, direct bf16 out.
// Q carries QSCALE (1/8 * log2e) -> softmax body = exp2f(min(s,60)).
// Shared Pb across the wave's 2 chains (46 KB LDS, r11-verified).
// ---------------------------------------------------------------------------
__global__ __launch_bounds__(256) void attn_kernel(
        const bf16* __restrict__ Q, const bf16* __restrict__ K,
        const bf16* __restrict__ VT, bf16* __restrict__ Out) {
    __shared__ __align__(16) bf16 Ks[2][64 * 72];
    __shared__ __align__(16) bf16 Vs[2][64 * 72];
    __shared__ __align__(16) bf16 Pb[4][16 * 72];
    int tid  = threadIdx.x;
    int wid  = tid >> 6, lane = tid & 63;
    int quad = lane >> 4, l15 = lane & 15;
    int bh = blockIdx.y;
    int qb = blockIdx.x * 128 + wid * 32;

    const bf16* Qh = Q  + (size_t)bh * SEQ * DHEAD;
    const bf16* Kh = K  + (size_t)bh * SEQ * DHEAD;
    const bf16* Vh = VT + (size_t)bh * DHEAD * SEQ;

    bf16x8 bQ0[2], bQ1[2];
#pragma unroll
    for (int c = 0; c < 2; c++) {
        const bf16* qp = &Qh[(qb + c * 16 + l15) * DHEAD + quad * 8];
        bQ0[c] = *(const bf16x8*)qp;
        bQ1[c] = *(const bf16x8*)(qp + 32);
    }

    int cc0 = tid * 2, cc1 = cc0 + 1;
    int kr0 = cc0 >> 3, kc0 = (cc0 & 7) * 8;
    int kr1 = cc1 >> 3, kc1 = (cc1 & 7) * 8;

    float lrow[2] = {0.f, 0.f};
    f32x4 Oacc[2][4] = {};

    {
        uint4 ka0 = *(const uint4*)&Kh[(size_t)kr0 * DHEAD + kc0];
        uint4 ka1 = *(const uint4*)&Kh[(size_t)kr1 * DHEAD + kc1];
        uint4 va0 = *(const uint4*)&Vh[(size_t)kr0 * SEQ + kc0];
        uint4 va1 = *(const uint4*)&Vh[(size_t)kr1 * SEQ + kc1];
        *(uint4*)&Ks[0][kr0 * 72 + kc0] = ka0;
        *(uint4*)&Ks[0][kr1 * 72 + kc1] = ka1;
        *(uint4*)&Vs[0][kr0 * 72 + kc0] = va0;
        *(uint4*)&Vs[0][kr1 * 72 + kc1] = va1;
    }
    __syncthreads();

    for (int it = 0; it < SEQ / 64; it++) {
        int cur = it & 1, nxt = cur ^ 1;
        int kb = (it + 1) * 64;
        uint4 nk0, nk1, nv0, nv1;
        bool pf = (it + 1 < SEQ / 64);
        if (pf) {
            nk0 = *(const uint4*)&Kh[(size_t)(kb + kr0) * DHEAD + kc0];
            nk1 = *(const uint4*)&Kh[(size_t)(kb + kr1) * DHEAD + kc1];
            nv0 = *(const uint4*)&Vh[(size_t)kr0 * SEQ + kb + kc0];
            nv1 = *(const uint4*)&Vh[(size_t)kr1 * SEQ + kb + kc1];
        }

        bf16x8 aK0[4], aK1[4], bV0[4], bV1[4];
#pragma unroll
        for (int t = 0; t < 4; t++) {
            const bf16* kp = &Ks[cur][(t * 16 + l15) * 72 + quad * 8];
            aK0[t] = *(const bf16x8*)kp;
            aK1[t] = *(const bf16x8*)(kp + 32);
            const bf16* vp = &Vs[cur][(t * 16 + l15) * 72 + quad * 8];
            bV0[t] = *(const bf16x8*)vp;
            bV1[t] = *(const bf16x8*)(vp + 32);
        }

#pragma unroll
        for (int c = 0; c < 2; c++) {
            f32x4 st[4];
#pragma unroll
            for (int t = 0; t < 4; t++) {
                f32x4 zv = {0.f, 0.f, 0.f, 0.f};
                st[t] = mfma16(aK1[t], bQ1[c], mfma16(aK0[t], bQ0[c], zv));
            }
            bf16* myP = Pb[wid];
#pragma unroll
            for (int t = 0; t < 4; t++) {
                bf16x4 pk;
                float ps = 0.f;
#pragma unroll
                for (int r = 0; r < 4; r++) {
                    float p = exp2f(fminf(st[t][r], 60.f));
                    ps += p;
                    pk[r] = (bf16)p;
                }
                lrow[c] += ps;
                *(bf16x4*)&myP[l15 * 72 + t * 16 + quad * 4] = pk;
            }
            // chain c+1's stores can't pass these reads (wave-local in-order DS)
            bf16x8 aP0 = *(const bf16x8*)&myP[l15 * 72 + quad * 8];
            bf16x8 aP1 = *(const bf16x8*)&myP[l15 * 72 + 32 + quad * 8];
#pragma unroll
            for (int nt = 0; nt < 4; nt++)
                Oacc[c][nt] = mfma16(aP1, bV1[nt],
                                     mfma16(aP0, bV0[nt], Oacc[c][nt]));
        }

        if (pf) {
            *(uint4*)&Ks[nxt][kr0 * 72 + kc0] = nk0;
            *(uint4*)&Ks[nxt][kr1 * 72 + kc1] = nk1;
            *(uint4*)&Vs[nxt][kr0 * 72 + kc0] = nv0;
            *(uint4*)&Vs[nxt][kr1 * 72 + kc1] = nv1;
        }
        __syncthreads();
    }

    int b = bh >> 3, hd = bh & 7;
#pragma unroll
    for (int c = 0; c < 2; c++) {
        float l = lrow[c];
        l += __shfl_xor(l, 16);
        l += __shfl_xor(l, 32);
        float linv[4];
#pragma unroll
        for (int r = 0; r < 4; r++)
            linv[r] = 1.f / __shfl(l, quad * 4 + r);
#pragma unroll
        for (int nt = 0; nt < 4; nt++)
#pragma unroll
            for (int r = 0; r < 4; r++) {
                int s = qb + c * 16 + quad * 4 + r;
                Out[((size_t)(b * SEQ + s)) * DMODEL + hd * 64 + nt * 16 + l15]
                    = (bf16)(Oacc[c][nt][r] * linv[r]);
            }
    }
}

// ---------------------------------------------------------------------------
// Residual + LayerNorm (unbiased std ddof=1, eps added to std).
// ---------------------------------------------------------------------------
__global__ __launch_bounds__(256) void ln_kernel(
        const bf16* __restrict__ X, const bf16* __restrict__ T,
        const bf16* __restrict__ Al, const bf16* __restrict__ Bl,
        void* __restrict__ Out, int final_out) {
    int wid = threadIdx.x >> 6, lane = threadIdx.x & 63;
    int row = blockIdx.x * 4 + wid;
    const bf16* xr = X + (size_t)row * DMODEL;
    const bf16* tr = T + (size_t)row * DMODEL;
    bf16x8 xv = *(const bf16x8*)&xr[lane * 8];
    bf16x8 tv = *(const bf16x8*)&tr[lane * 8];
    float v[8];
#pragma unroll
    for (int i = 0; i < 8; i++) v[i] = (float)xv[i] + (float)tv[i];
    float sum = 0.f, sq = 0.f;
#pragma unroll
    for (int i = 0; i < 8; i++) { sum += v[i]; sq += v[i] * v[i]; }
#pragma unroll
    for (int m = 1; m < 64; m <<= 1) {
        sum += __shfl_xor(sum, m);
        sq  += __shfl_xor(sq,  m);
    }
    float mean = sum * (1.f / DMODEL);
    float var  = (sq - DMODEL * mean * mean) * (1.f / (DMODEL - 1));
    var = var > 0.f ? var : 0.f;
    float inv = 1.f / (sqrtf(var) + 1e-6f);
#pragma unroll
    for (int i = 0; i < 8; i++) {
        int c = lane * 8 + i;
        float yv = (float)Al[c] * (v[i] - mean) * inv + (float)Bl[c];
        yv = fminf(fmaxf(yv, -1e4f), 1e4f);
        size_t idx = (size_t)row * DMODEL + c;
        if (final_out) ((float*)Out)[idx] = yv;
        else           ((bf16*)Out)[idx]  = (bf16)yv;
    }
}

// ---------------------------------------------------------------------------
extern "C" void kernel_launch(void* const* d_in, const int* in_sizes, int n_in,
                              void* d_out, int out_size, void* d_ws, size_t ws_size,
                              hipStream_t stream) {
    if (ws_size < WS_NEED) {
        sentinel_kernel<<<1, 64, 0, stream>>>((bf16*)d_out);
        return;
    }

    const float* x  = (const float*)d_in[0];
    const float* wq = (const float*)d_in[1],  *bq = (const float*)d_in[2];
    const float* wk = (const float*)d_in[3],  *bk = (const float*)d_in[4];
    const float* wv = (const float*)d_in[5],  *bv = (const float*)d_in[6];
    const float* wo = (const float*)d_in[7],  *bo = (const float*)d_in[8];
    const float* w1 = (const float*)d_in[9],  *b1 = (const float*)d_in[10];
    const float* w2 = (const float*)d_in[11], *b2 = (const float*)d_in[12];
    const float* ln1a = (const float*)d_in[13], *ln1b = (const float*)d_in[14];
    const float* ln2a = (const float*)d_in[15], *ln2b = (const float*)d_in[16];

    char* ws = (char*)d_ws;
    bf16* wT   = (bf16*)(ws + 0);
    bf16* woT  = (bf16*)(ws + 1572864);
    bf16* w1T  = (bf16*)(ws + 2097152);
    bf16* w2T  = (bf16*)(ws + 4194304);
    bf16* xcv  = (bf16*)(ws + 6291456);
    bf16* prm  = (bf16*)(ws + 14680064);
    bf16* regA = (bf16*)(ws + 14696448);
    bf16* regB = (bf16*)(ws + 23085056);
    bf16* regC = (bf16*)(ws + 31473664);
    bf16* ff1  = (bf16*)(ws + 39862272);
    bf16* aout = (bf16*)d_out;   // scratch (fully overwritten by final LN)

    bf16 *pbq = prm, *pbo = prm + 1536;
    bf16 *pb1 = prm + 2048, *pb2 = prm + 4096;
    bf16 *pl1a = prm + 4608, *pl1b = prm + 5120;
    bf16 *pl2a = prm + 5632, *pl2b = prm + 6144;

    prep_kernel<<<7178, 256, 0, stream>>>(x, wq, wk, wv, wo, w1, w2,
                                          bq, bk, bv, bo, b1, b2,
                                          ln1a, ln1b, ln2a, ln2b,
                                          xcv, wT, w1T, w2T, prm);

    // fused QKV projection (Q pre-scaled by QSCALE; V^T coalesced epilogue)
    gemm_qkv<<<dim3(64, 12), 256, 0, stream>>>(xcv, wT, pbq,
                                               regA, regB, regC,
                                               MTOT, 3 * DMODEL, DMODEL);

    // attention -> d_out (scratch), direct bf16
    attn_kernel<<<dim3(SEQ / 128, NBATCH * NHEADS), 256, 0, stream>>>(
        regA, regB, regC, aout);

    // O-proj: aout -> t (regA); BM=64/BK=64
    gemm_bt64<false><<<dim3(128, 4), 256, 0, stream>>>(aout, woT, pbo, regA,
                                                       MTOT, DMODEL, DMODEL);

    // LN1: xcv + t -> y (regB)
    ln_kernel<<<MTOT / 4, 256, 0, stream>>>(xcv, regA, pl1a, pl1b, regB, 0);

    // FFN: y -> ff1 -> ff2 (regA)
    gemm_bt<true ><<<dim3(64, 16), 256, 0, stream>>>(regB, w1T, pb1, ff1,
                                                     MTOT, DFF, DMODEL);
    gemm_bt64<false><<<dim3(128, 4), 256, 0, stream>>>(ff1, w2T, pb2, regA,
                                                       MTOT, DMODEL, DFF);

    // LN2: y + ff2 -> out (fp32)
    ln_kernel<<<MTOT / 4, 256, 0, stream>>>(regB, regA, pl2a, pl2b, d_out, 1);
}

// Round 13
// 285.124 us; speedup vs baseline: 1.0766x; 1.0766x over previous
//
#include <hip/hip_runtime.h>
#include <hip/hip_bf16.h>

// ---------------------------------------------------------------------------
// EncoderBlock on MI355X (gfx950). Round 13.
// r12 post-mortem: exp2f() is the PRECISE ocml call (range-fixup branches,
// +16 VGPR, VALUBusy 52->61%) -> attn regressed 66->83 us. Fix: raw
// instruction via __builtin_amdgcn_exp2f -> one v_min + one v_exp per
// element. QSCALE folding and BK=64 GEMMs (mildly positive) kept.
//
// ws layout (bytes), WS_NEED = 73416704, sentinel-guarded:
//   [0,        2097152)  wq|wk|wv|wo T (bf16)
//   [2097152,  4194304)  w1T
//   [4194304,  6291456)  w2T
//   [6291456, 14680064)  xcv: x as bf16 (8 MB)
//   [14680064,14696448)  small params (bf16)
//   A [14696448,23085056) qbuf -> t -> ff2      (8 MB)
//   B [23085056,31473664) kbuf -> y             (8 MB)
//   C [31473664,39862272) vT                    (8 MB)
//   F [39862272,73416704) ff1 (32 MB)
//   d_out                attn output scratch (bf16) -> final output (fp32)
// ---------------------------------------------------------------------------

typedef __bf16 bf16;
typedef __bf16 bf16x4 __attribute__((ext_vector_type(4)));
typedef __bf16 bf16x8 __attribute__((ext_vector_type(8)));
typedef float  f32x4  __attribute__((ext_vector_type(4)));

#define NBATCH 4
#define SEQ    2048
#define DMODEL 512
#define NHEADS 8
#define DHEAD  64
#define DFF    2048
#define MTOT   (NBATCH * SEQ)   // 8192
#define WS_NEED 73416704u
#define QSCALE (0.125f * 1.44269504f)   // 1/sqrt(dk) * log2(e), folded into Q

__device__ __forceinline__ f32x4 mfma16(bf16x8 a, bf16x8 b, f32x4 c) {
    return __builtin_amdgcn_mfma_f32_16x16x32_bf16(a, b, c, 0, 0, 0);
}

// async global->LDS, 16 B/lane. LDS dest = wave-uniform base + lane*16.
__device__ __forceinline__ void lds16(const bf16* g, bf16* l) {
    __builtin_amdgcn_global_load_lds(
        (const __attribute__((address_space(1))) void*)g,
        (__attribute__((address_space(3))) void*)l, 16, 0, 0);
}

__device__ __forceinline__ float scrub(float f) {
    return (fabsf(f) < 1e30f) ? f : 0.f;   // NaN/Inf -> 0 (no-op valid data)
}

__global__ void sentinel_kernel(bf16* out) {
    out[threadIdx.x] = (bf16)1000.0f;
}

// ---------------------------------------------------------------------------
// prep: x convert + small-param converts + all 6 weight transposes, ONE launch
// ---------------------------------------------------------------------------
__global__ __launch_bounds__(256) void prep_kernel(
        const float* x,
        const float* wq, const float* wk, const float* wv, const float* wo,
        const float* w1, const float* w2,
        const float* bq, const float* bk, const float* bv, const float* bo,
        const float* b1, const float* b2,
        const float* l1a, const float* l1b, const float* l2a, const float* l2b,
        bf16* __restrict__ xcv,
        bf16* __restrict__ wT, bf16* __restrict__ w1T, bf16* __restrict__ w2T,
        bf16* __restrict__ prm) {
    __shared__ bf16 tile[32][33];
    int b = blockIdx.x;
    if (b < 4096) {
        int i = (b * 256 + threadIdx.x) * 4;
        float4 f = *(const float4*)(x + i);
        bf16x4 o = {(bf16)scrub(f.x), (bf16)scrub(f.y),
                    (bf16)scrub(f.z), (bf16)scrub(f.w)};
        *(bf16x4*)(xcv + i) = o;
        return;
    }
    if (b < 4106) {
        int pb = b - 4096;
        const float* srcs[10] = {bq, bk, bv, bo, b1, b2, l1a, l1b, l2a, l2b};
        const int len[10] = {512,512,512,512,2048,512,512,512,512,512};
        const int dst[10] = {0,512,1024,1536,2048,4096,4608,5120,5632,6144};
        const float* s = srcs[pb];
        bf16* d = prm + dst[pb];
        for (int i = threadIdx.x; i < len[pb]; i += 256)
            d[i] = (bf16)scrub(s[i]);
        return;
    }
    const float* in; bf16* out; int K, N, bx, by;
    if (b < 5130) {
        int idx = b - 4106, z = idx >> 8, rem = idx & 255;
        const float* srcs[4] = {wq, wk, wv, wo};
        in = srcs[z]; out = wT + (size_t)z * 262144;
        K = 512; N = 512; bx = rem & 15; by = rem >> 4;
    } else if (b < 6154) {
        int idx = b - 5130;
        in = w1; out = w1T; K = 512; N = 2048; bx = idx & 63; by = idx >> 6;
    } else {
        int idx = b - 6154;
        in = w2; out = w2T; K = 2048; N = 512; bx = idx & 15; by = idx >> 4;
    }
    int tx = threadIdx.x & 31, ty = threadIdx.x >> 5;
    int n0 = bx * 32, k0 = by * 32;
#pragma unroll
    for (int i = 0; i < 4; i++) {
        int kl = ty * 4 + i;
        tile[kl][tx] = (bf16)scrub(in[(size_t)(k0 + kl) * N + n0 + tx]);
    }
    __syncthreads();
#pragma unroll
    for (int i = 0; i < 4; i++) {
        int nl = ty * 4 + i;
        out[(size_t)(n0 + nl) * K + k0 + tx] = tile[tx][nl];
    }
}

// ---------------------------------------------------------------------------
// 128x128 GEMM, BK=64 via paired stride-32 sub-buffers; two frag passes per
// barrier pair (same regs as BK=32, half the barriers).
// ---------------------------------------------------------------------------
template <bool RELU>
__global__ __launch_bounds__(256) void gemm_bt(
        const bf16* __restrict__ A, const bf16* __restrict__ BT,
        const bf16* __restrict__ bias, bf16* __restrict__ Cout,
        int M, int N, int K) {
    constexpr int BM = 128, BN = 128;
    __shared__ __align__(16) bf16 As0[BM * 32], As1[BM * 32];
    __shared__ __align__(16) bf16 Bs0[BN * 32], Bs1[BN * 32];

    int tid  = threadIdx.x;
    int wid  = tid >> 6, lane = tid & 63;
    int quad = lane >> 4, l15 = lane & 15;
    int mb = blockIdx.x * BM, nb = blockIdx.y * BN;
    int wm = (wid >> 1) * 64, wn = (wid & 1) * 64;

    f32x4 acc[4][4] = {};

    int c0 = wid * 128 + lane, c1 = c0 + 64;
    int ar0 = c0 >> 2, ac0 = (c0 & 3) * 8;
    int ar1 = c1 >> 2, ac1 = (c1 & 3) * 8;
    int o0 = wid * 1024, o1 = wid * 1024 + 512;

    for (int k0 = 0; k0 < K; k0 += 64) {
        __syncthreads();
        lds16(&A [(size_t)(mb + ar0) * K + k0 + ac0],      &As0[o0]);
        lds16(&A [(size_t)(mb + ar1) * K + k0 + ac1],      &As0[o1]);
        lds16(&A [(size_t)(mb + ar0) * K + k0 + 32 + ac0], &As1[o0]);
        lds16(&A [(size_t)(mb + ar1) * K + k0 + 32 + ac1], &As1[o1]);
        lds16(&BT[(size_t)(nb + ar0) * K + k0 + ac0],      &Bs0[o0]);
        lds16(&BT[(size_t)(nb + ar1) * K + k0 + ac1],      &Bs0[o1]);
        lds16(&BT[(size_t)(nb + ar0) * K + k0 + 32 + ac0], &Bs1[o0]);
        lds16(&BT[(size_t)(nb + ar1) * K + k0 + 32 + ac1], &Bs1[o1]);
        __syncthreads();

        bf16x8 af[4], bfr[4];
#pragma unroll
        for (int i = 0; i < 4; i++)
            af[i] = *(const bf16x8*)&As0[(wm + i * 16 + l15) * 32 + quad * 8];
#pragma unroll
        for (int j = 0; j < 4; j++)
            bfr[j] = *(const bf16x8*)&Bs0[(wn + j * 16 + l15) * 32 + quad * 8];
#pragma unroll
        for (int i = 0; i < 4; i++)
#pragma unroll
            for (int j = 0; j < 4; j++)
                acc[i][j] = mfma16(af[i], bfr[j], acc[i][j]);
#pragma unroll
        for (int i = 0; i < 4; i++)
            af[i] = *(const bf16x8*)&As1[(wm + i * 16 + l15) * 32 + quad * 8];
#pragma unroll
        for (int j = 0; j < 4; j++)
            bfr[j] = *(const bf16x8*)&Bs1[(wn + j * 16 + l15) * 32 + quad * 8];
#pragma unroll
        for (int i = 0; i < 4; i++)
#pragma unroll
            for (int j = 0; j < 4; j++)
                acc[i][j] = mfma16(af[i], bfr[j], acc[i][j]);
    }

#pragma unroll
    for (int j = 0; j < 4; j++) {
        int n = nb + wn + j * 16 + l15;
        float bv = (float)bias[n];
#pragma unroll
        for (int i = 0; i < 4; i++) {
            int mBase = mb + wm + i * 16 + quad * 4;
#pragma unroll
            for (int r = 0; r < 4; r++) {
                float v = acc[i][j][r] + bv;
                if (RELU) v = v > 0.f ? v : 0.f;
                Cout[(size_t)(mBase + r) * N + n] = (bf16)v;
            }
        }
    }
}

// ---------------------------------------------------------------------------
// BM=64, BK=64 GEMM (r11-verified) for O-proj / FFN2.
// ---------------------------------------------------------------------------
template <bool RELU>
__global__ __launch_bounds__(256) void gemm_bt64(
        const bf16* __restrict__ A, const bf16* __restrict__ BT,
        const bf16* __restrict__ bias, bf16* __restrict__ Cout,
        int M, int N, int K) {
    constexpr int BM = 64, BN = 128;
    __shared__ __align__(16) bf16 As0[BM * 32], As1[BM * 32];
    __shared__ __align__(16) bf16 Bs0[BN * 32], Bs1[BN * 32];

    int tid  = threadIdx.x;
    int wid  = tid >> 6, lane = tid & 63;
    int quad = lane >> 4, l15 = lane & 15;
    int mb = blockIdx.x * BM, nb = blockIdx.y * BN;
    int wm = (wid >> 1) * 32, wn = (wid & 1) * 64;

    f32x4 acc[2][4] = {};

    int cA = wid * 64 + lane;
    int arA = cA >> 2, acA = (cA & 3) * 8;
    int cB0 = wid * 128 + lane, cB1 = cB0 + 64;
    int br0 = cB0 >> 2, bc0 = (cB0 & 3) * 8;
    int br1 = cB1 >> 2, bc1 = (cB1 & 3) * 8;

    for (int k0 = 0; k0 < K; k0 += 64) {
        __syncthreads();
        lds16(&A [(size_t)(mb + arA) * K + k0 + acA],      &As0[wid * 512]);
        lds16(&A [(size_t)(mb + arA) * K + k0 + 32 + acA], &As1[wid * 512]);
        lds16(&BT[(size_t)(nb + br0) * K + k0 + bc0],      &Bs0[wid * 1024]);
        lds16(&BT[(size_t)(nb + br1) * K + k0 + bc1],      &Bs0[wid * 1024 + 512]);
        lds16(&BT[(size_t)(nb + br0) * K + k0 + 32 + bc0], &Bs1[wid * 1024]);
        lds16(&BT[(size_t)(nb + br1) * K + k0 + 32 + bc1], &Bs1[wid * 1024 + 512]);
        __syncthreads();

        bf16x8 a0[2], a1[2], b0[4], b1[4];
#pragma unroll
        for (int i = 0; i < 2; i++) {
            a0[i] = *(const bf16x8*)&As0[(wm + i * 16 + l15) * 32 + quad * 8];
            a1[i] = *(const bf16x8*)&As1[(wm + i * 16 + l15) * 32 + quad * 8];
        }
#pragma unroll
        for (int j = 0; j < 4; j++) {
            b0[j] = *(const bf16x8*)&Bs0[(wn + j * 16 + l15) * 32 + quad * 8];
            b1[j] = *(const bf16x8*)&Bs1[(wn + j * 16 + l15) * 32 + quad * 8];
        }
#pragma unroll
        for (int i = 0; i < 2; i++)
#pragma unroll
            for (int j = 0; j < 4; j++)
                acc[i][j] = mfma16(a1[i], b1[j], mfma16(a0[i], b0[j], acc[i][j]));
    }

#pragma unroll
    for (int j = 0; j < 4; j++) {
        int n = nb + wn + j * 16 + l15;
        float bv = (float)bias[n];
#pragma unroll
        for (int i = 0; i < 2; i++) {
            int mBase = mb + wm + i * 16 + quad * 4;
#pragma unroll
            for (int r = 0; r < 4; r++) {
                float v = acc[i][j][r] + bv;
                if (RELU) v = v > 0.f ? v : 0.f;
                Cout[(size_t)(mBase + r) * N + n] = (bf16)v;
            }
        }
    }
}

// ---------------------------------------------------------------------------
// Fused QKV GEMM, BK=64: region 0 -> Q*(QSCALE), 1 -> K, 2 -> V^T via
// LDS-transposed coalesced epilogue.
// ---------------------------------------------------------------------------
__global__ __launch_bounds__(256) void gemm_qkv(
        const bf16* __restrict__ A, const bf16* __restrict__ BT,
        const bf16* __restrict__ bias,
        bf16* __restrict__ Cq, bf16* __restrict__ Ck, bf16* __restrict__ Cv,
        int M, int N, int K) {
    constexpr int BM = 128, BN = 128;
    __shared__ __align__(16) bf16 As0[BM * 32], As1[BM * 32];
    __shared__ __align__(16) bf16 Bs0[BN * 32], Bs1[BN * 32];
    __shared__ __align__(16) bf16 Ts[128 * 136];

    int tid  = threadIdx.x;
    int wid  = tid >> 6, lane = tid & 63;
    int quad = lane >> 4, l15 = lane & 15;
    int mb = blockIdx.x * BM, nb = blockIdx.y * BN;
    int wm = (wid >> 1) * 64, wn = (wid & 1) * 64;

    f32x4 acc[4][4] = {};

    int c0 = wid * 128 + lane, c1 = c0 + 64;
    int ar0 = c0 >> 2, ac0 = (c0 & 3) * 8;
    int ar1 = c1 >> 2, ac1 = (c1 & 3) * 8;
    int o0 = wid * 1024, o1 = wid * 1024 + 512;

    for (int k0 = 0; k0 < K; k0 += 64) {
        __syncthreads();
        lds16(&A [(size_t)(mb + ar0) * K + k0 + ac0],      &As0[o0]);
        lds16(&A [(size_t)(mb + ar1) * K + k0 + ac1],      &As0[o1]);
        lds16(&A [(size_t)(mb + ar0) * K + k0 + 32 + ac0], &As1[o0]);
        lds16(&A [(size_t)(mb + ar1) * K + k0 + 32 + ac1], &As1[o1]);
        lds16(&BT[(size_t)(nb + ar0) * K + k0 + ac0],      &Bs0[o0]);
        lds16(&BT[(size_t)(nb + ar1) * K + k0 + ac1],      &Bs0[o1]);
        lds16(&BT[(size_t)(nb + ar0) * K + k0 + 32 + ac0], &Bs1[o0]);
        lds16(&BT[(size_t)(nb + ar1) * K + k0 + 32 + ac1], &Bs1[o1]);
        __syncthreads();

        bf16x8 af[4], bfr[4];
#pragma unroll
        for (int i = 0; i < 4; i++)
            af[i] = *(const bf16x8*)&As0[(wm + i * 16 + l15) * 32 + quad * 8];
#pragma unroll
        for (int j = 0; j < 4; j++)
            bfr[j] = *(const bf16x8*)&Bs0[(wn + j * 16 + l15) * 32 + quad * 8];
#pragma unroll
        for (int i = 0; i < 4; i++)
#pragma unroll
            for (int j = 0; j < 4; j++)
                acc[i][j] = mfma16(af[i], bfr[j], acc[i][j]);
#pragma unroll
        for (int i = 0; i < 4; i++)
            af[i] = *(const bf16x8*)&As1[(wm + i * 16 + l15) * 32 + quad * 8];
#pragma unroll
        for (int j = 0; j < 4; j++)
            bfr[j] = *(const bf16x8*)&Bs1[(wn + j * 16 + l15) * 32 + quad * 8];
#pragma unroll
        for (int i = 0; i < 4; i++)
#pragma unroll
            for (int j = 0; j < 4; j++)
                acc[i][j] = mfma16(af[i], bfr[j], acc[i][j]);
    }

    int reg = nb >> 9;   // 0=Q, 1=K, 2=V
    if (reg < 2) {
        bf16* C = reg ? Ck : Cq;
        float scl = reg ? 1.0f : QSCALE;
#pragma unroll
        for (int j = 0; j < 4; j++) {
            int n = nb + wn + j * 16 + l15;
            float bv = (float)bias[n];
            int nn = n & 511;
            int h = nn >> 6, dk = nn & 63;
#pragma unroll
            for (int i = 0; i < 4; i++) {
                int mBase = mb + wm + i * 16 + quad * 4;
#pragma unroll
                for (int r = 0; r < 4; r++) {
                    float v = (acc[i][j][r] + bv) * scl;
                    int m = mBase + r;
                    int b = m >> 11, s = m & (SEQ - 1);
                    C[((size_t)(b * NHEADS + h) * SEQ + s) * DHEAD + dk] = (bf16)v;
                }
            }
        }
    } else {
#pragma unroll
        for (int j = 0; j < 4; j++) {
            int nl = wn + j * 16 + l15;
            float bv = (float)bias[nb + nl];
#pragma unroll
            for (int i = 0; i < 4; i++) {
                int ml = wm + i * 16 + quad * 4;
                bf16x4 pk;
#pragma unroll
                for (int r = 0; r < 4; r++) pk[r] = (bf16)(acc[i][j][r] + bv);
                *(bf16x4*)&Ts[nl * 136 + ml] = pk;
            }
        }
        __syncthreads();
        int nl = tid >> 1, half = tid & 1;
        int nn = (nb + nl) & 511;
        int h = nn >> 6, dk = nn & 63;
        int bb = mb >> 11, s0 = mb & (SEQ - 1);
        bf16* dst = &Cv[((size_t)(bb * NHEADS + h) * DHEAD + dk) * SEQ + s0 + half * 64];
        const bf16* srcl = &Ts[nl * 136 + half * 64];
#pragma unroll
        for (int v = 0; v < 8; v++)
            *(uint4*)(dst + v * 8) = *(const uint4*)(srcl + v * 8);
    }
}

// ---------------------------------------------------------------------------
// Flash attention: grid (SEQ/128, B*H), block 256 = 4 waves, direct bf16 out.
// Q carries QSCALE (1/8 * log2e); softmax body = v_min + v_exp via
// __builtin_amdgcn_exp2f (raw instruction — exp2f() libm call regressed r12).
// Shared Pb across the wave's 2 chains (46 KB LDS, r11-verified).
// ---------------------------------------------------------------------------
__global__ __launch_bounds__(256) void attn_kernel(
        const bf16* __restrict__ Q, const bf16* __restrict__ K,
        const bf16* __restrict__ VT, bf16* __restrict__ Out) {
    __shared__ __align__(16) bf16 Ks[2][64 * 72];
    __shared__ __align__(16) bf16 Vs[2][64 * 72];
    __shared__ __align__(16) bf16 Pb[4][16 * 72];
    int tid  = threadIdx.x;
    int wid  = tid >> 6, lane = tid & 63;
    int quad = lane >> 4, l15 = lane & 15;
    int bh = blockIdx.y;
    int qb = blockIdx.x * 128 + wid * 32;

    const bf16* Qh = Q  + (size_t)bh * SEQ * DHEAD;
    const bf16* Kh = K  + (size_t)bh * SEQ * DHEAD;
    const bf16* Vh = VT + (size_t)bh * DHEAD * SEQ;

    bf16x8 bQ0[2], bQ1[2];
#pragma unroll
    for (int c = 0; c < 2; c++) {
        const bf16* qp = &Qh[(qb + c * 16 + l15) * DHEAD + quad * 8];
        bQ0[c] = *(const bf16x8*)qp;
        bQ1[c] = *(const bf16x8*)(qp + 32);
    }

    int cc0 = tid * 2, cc1 = cc0 + 1;
    int kr0 = cc0 >> 3, kc0 = (cc0 & 7) * 8;
    int kr1 = cc1 >> 3, kc1 = (cc1 & 7) * 8;

    float lrow[2] = {0.f, 0.f};
    f32x4 Oacc[2][4] = {};

    {
        uint4 ka0 = *(const uint4*)&Kh[(size_t)kr0 * DHEAD + kc0];
        uint4 ka1 = *(const uint4*)&Kh[(size_t)kr1 * DHEAD + kc1];
        uint4 va0 = *(const uint4*)&Vh[(size_t)kr0 * SEQ + kc0];
        uint4 va1 = *(const uint4*)&Vh[(size_t)kr1 * SEQ + kc1];
        *(uint4*)&Ks[0][kr0 * 72 + kc0] = ka0;
        *(uint4*)&Ks[0][kr1 * 72 + kc1] = ka1;
        *(uint4*)&Vs[0][kr0 * 72 + kc0] = va0;
        *(uint4*)&Vs[0][kr1 * 72 + kc1] = va1;
    }
    __syncthreads();

    for (int it = 0; it < SEQ / 64; it++) {
        int cur = it & 1, nxt = cur ^ 1;
        int kb = (it + 1) * 64;
        uint4 nk0, nk1, nv0, nv1;
        bool pf = (it + 1 < SEQ / 64);
        if (pf) {
            nk0 = *(const uint4*)&Kh[(size_t)(kb + kr0) * DHEAD + kc0];
            nk1 = *(const uint4*)&Kh[(size_t)(kb + kr1) * DHEAD + kc1];
            nv0 = *(const uint4*)&Vh[(size_t)kr0 * SEQ + kb + kc0];
            nv1 = *(const uint4*)&Vh[(size_t)kr1 * SEQ + kb + kc1];
        }

        bf16x8 aK0[4], aK1[4], bV0[4], bV1[4];
#pragma unroll
        for (int t = 0; t < 4; t++) {
            const bf16* kp = &Ks[cur][(t * 16 + l15) * 72 + quad * 8];
            aK0[t] = *(const bf16x8*)kp;
            aK1[t] = *(const bf16x8*)(kp + 32);
            const bf16* vp = &Vs[cur][(t * 16 + l15) * 72 + quad * 8];
            bV0[t] = *(const bf16x8*)vp;
            bV1[t] = *(const bf16x8*)(vp + 32);
        }

#pragma unroll
        for (int c = 0; c < 2; c++) {
            f32x4 st[4];
#pragma unroll
            for (int t = 0; t < 4; t++) {
                f32x4 zv = {0.f, 0.f, 0.f, 0.f};
                st[t] = mfma16(aK1[t], bQ1[c], mfma16(aK0[t], bQ0[c], zv));
            }
            bf16* myP = Pb[wid];
#pragma unroll
            for (int t = 0; t < 4; t++) {
                bf16x4 pk;
                float ps = 0.f;
#pragma unroll
                for (int r = 0; r < 4; r++) {
                    float p = __builtin_amdgcn_exp2f(fminf(st[t][r], 60.f));
                    ps += p;
                    pk[r] = (bf16)p;
                }
                lrow[c] += ps;
                *(bf16x4*)&myP[l15 * 72 + t * 16 + quad * 4] = pk;
            }
            // chain c+1's stores can't pass these reads (wave-local in-order DS)
            bf16x8 aP0 = *(const bf16x8*)&myP[l15 * 72 + quad * 8];
            bf16x8 aP1 = *(const bf16x8*)&myP[l15 * 72 + 32 + quad * 8];
#pragma unroll
            for (int nt = 0; nt < 4; nt++)
                Oacc[c][nt] = mfma16(aP1, bV1[nt],
                                     mfma16(aP0, bV0[nt], Oacc[c][nt]));
        }

        if (pf) {
            *(uint4*)&Ks[nxt][kr0 * 72 + kc0] = nk0;
            *(uint4*)&Ks[nxt][kr1 * 72 + kc1] = nk1;
            *(uint4*)&Vs[nxt][kr0 * 72 + kc0] = nv0;
            *(uint4*)&Vs[nxt][kr1 * 72 + kc1] = nv1;
        }
        __syncthreads();
    }

    int b = bh >> 3, hd = bh & 7;
#pragma unroll
    for (int c = 0; c < 2; c++) {
        float l = lrow[c];
        l += __shfl_xor(l, 16);
        l += __shfl_xor(l, 32);
        float linv[4];
#pragma unroll
        for (int r = 0; r < 4; r++)
            linv[r] = 1.f / __shfl(l, quad * 4 + r);
#pragma unroll
        for (int nt = 0; nt < 4; nt++)
#pragma unroll
            for (int r = 0; r < 4; r++) {
                int s = qb + c * 16 + quad * 4 + r;
                Out[((size_t)(b * SEQ + s)) * DMODEL + hd * 64 + nt * 16 + l15]
                    = (bf16)(Oacc[c][nt][r] * linv[r]);
            }
    }
}

// ---------------------------------------------------------------------------
// Residual + LayerNorm (unbiased std ddof=1, eps added to std).
// ---------------------------------------------------------------------------
__global__ __launch_bounds__(256) void ln_kernel(
        const bf16* __restrict__ X, const bf16* __restrict__ T,
        const bf16* __restrict__ Al, const bf16* __restrict__ Bl,
        void* __restrict__ Out, int final_out) {
    int wid = threadIdx.x >> 6, lane = threadIdx.x & 63;
    int row = blockIdx.x * 4 + wid;
    const bf16* xr = X + (size_t)row * DMODEL;
    const bf16* tr = T + (size_t)row * DMODEL;
    bf16x8 xv = *(const bf16x8*)&xr[lane * 8];
    bf16x8 tv = *(const bf16x8*)&tr[lane * 8];
    float v[8];
#pragma unroll
    for (int i = 0; i < 8; i++) v[i] = (float)xv[i] + (float)tv[i];
    float sum = 0.f, sq = 0.f;
#pragma unroll
    for (int i = 0; i < 8; i++) { sum += v[i]; sq += v[i] * v[i]; }
#pragma unroll
    for (int m = 1; m < 64; m <<= 1) {
        sum += __shfl_xor(sum, m);
        sq  += __shfl_xor(sq,  m);
    }
    float mean = sum * (1.f / DMODEL);
    float var  = (sq - DMODEL * mean * mean) * (1.f / (DMODEL - 1));
    var = var > 0.f ? var : 0.f;
    float inv = 1.f / (sqrtf(var) + 1e-6f);
#pragma unroll
    for (int i = 0; i < 8; i++) {
        int c = lane * 8 + i;
        float yv = (float)Al[c] * (v[i] - mean) * inv + (float)Bl[c];
        yv = fminf(fmaxf(yv, -1e4f), 1e4f);
        size_t idx = (size_t)row * DMODEL + c;
        if (final_out) ((float*)Out)[idx] = yv;
        else           ((bf16*)Out)[idx]  = (bf16)yv;
    }
}

// ---------------------------------------------------------------------------
extern "C" void kernel_launch(void* const* d_in, const int* in_sizes, int n_in,
                              void* d_out, int out_size, void* d_ws, size_t ws_size,
                              hipStream_t stream) {
    if (ws_size < WS_NEED) {
        sentinel_kernel<<<1, 64, 0, stream>>>((bf16*)d_out);
        return;
    }

    const float* x  = (const float*)d_in[0];
    const float* wq = (const float*)d_in[1],  *bq = (const float*)d_in[2];
    const float* wk = (const float*)d_in[3],  *bk = (const float*)d_in[4];
    const float* wv = (const float*)d_in[5],  *bv = (const float*)d_in[6];
    const float* wo = (const float*)d_in[7],  *bo = (const float*)d_in[8];
    const float* w1 = (const float*)d_in[9],  *b1 = (const float*)d_in[10];
    const float* w2 = (const float*)d_in[11], *b2 = (const float*)d_in[12];
    const float* ln1a = (const float*)d_in[13], *ln1b = (const float*)d_in[14];
    const float* ln2a = (const float*)d_in[15], *ln2b = (const float*)d_in[16];

    char* ws = (char*)d_ws;
    bf16* wT   = (bf16*)(ws + 0);
    bf16* woT  = (bf16*)(ws + 1572864);
    bf16* w1T  = (bf16*)(ws + 2097152);
    bf16* w2T  = (bf16*)(ws + 4194304);
    bf16* xcv  = (bf16*)(ws + 6291456);
    bf16* prm  = (bf16*)(ws + 14680064);
    bf16* regA = (bf16*)(ws + 14696448);
    bf16* regB = (bf16*)(ws + 23085056);
    bf16* regC = (bf16*)(ws + 31473664);
    bf16* ff1  = (bf16*)(ws + 39862272);
    bf16* aout = (bf16*)d_out;   // scratch (fully overwritten by final LN)

    bf16 *pbq = prm, *pbo = prm + 1536;
    bf16 *pb1 = prm + 2048, *pb2 = prm + 4096;
    bf16 *pl1a = prm + 4608, *pl1b = prm + 5120;
    bf16 *pl2a = prm + 5632, *pl2b = prm + 6144;

    prep_kernel<<<7178, 256, 0, stream>>>(x, wq, wk, wv, wo, w1, w2,
                                          bq, bk, bv, bo, b1, b2,
                                          ln1a, ln1b, ln2a, ln2b,
                                          xcv, wT, w1T, w2T, prm);

    // fused QKV projection (Q pre-scaled by QSCALE; V^T coalesced epilogue)
    gemm_qkv<<<dim3(64, 12), 256, 0, stream>>>(xcv, wT, pbq,
                                               regA, regB, regC,
                                               MTOT, 3 * DMODEL, DMODEL);

    // attention -> d_out (scratch), direct bf16
    attn_kernel<<<dim3(SEQ / 128, NBATCH * NHEADS), 256, 0, stream>>>(
        regA, regB, regC, aout);

    // O-proj: aout -> t (regA); BM=64/BK=64
    gemm_bt64<false><<<dim3(128, 4), 256, 0, stream>>>(aout, woT, pbo, regA,
                                                       MTOT, DMODEL, DMODEL);

    // LN1: xcv + t -> y (regB)
    ln_kernel<<<MTOT / 4, 256, 0, stream>>>(xcv, regA, pl1a, pl1b, regB, 0);

    // FFN: y -> ff1 -> ff2 (regA)
    gemm_bt<true ><<<dim3(64, 16), 256, 0, stream>>>(regB, w1T, pb1, ff1,
                                                     MTOT, DFF, DMODEL);
    gemm_bt64<false><<<dim3(128, 4), 256, 0, stream>>>(ff1, w2T, pb2, regA,
                                                       MTOT, DMODEL, DFF);

    // LN2: y + ff2 -> out (fp32)
    ln_kernel<<<MTOT / 4, 256, 0, stream>>>(regB, regA, pl2a, pl2b, d_out, 1);
}